// Round 6
// baseline (216.201 us; speedup 1.0000x reference)
//
#include <hip/hip_runtime.h>
#include <hip/hip_cooperative_groups.h>
#include <math.h>

namespace cg = cooperative_groups;

#define Bsz 8192
#define ROT2(x) ((((x) << 2) | ((x) >> 4)) & 63)   // 16-slot granule bank swizzle

typedef __attribute__((ext_vector_type(8))) short short8;   // 8 bf16 = 4 VGPR
typedef __attribute__((ext_vector_type(4))) float float4v;  // MFMA C/D frag

static constexpr float INV_T = 1.0f / 0.07f;  // logit scale; also fixed logsumexp shift

// RNE float->bf16 pack (x -> low16, y -> high16)
static __device__ inline unsigned pack_bf16(float x, float y) {
    union { float f; unsigned u; } a, b;
    a.f = x; b.f = y;
    unsigned ra = a.u + 0x7FFF + ((a.u >> 16) & 1);
    unsigned rb = b.u + 0x7FFF + ((b.u >> 16) & 1);
    return (ra >> 16) | (rb & 0xFFFF0000u);
}

// ============================================================================
// ONE cooperative kernel: 256 blocks x 1024 threads, 1 block/CU (LDS-forced).
// A: normalize/select/Yf-transpose  -> grid.sync
// B: deterministic compaction (prefix over cntArr), write Xb/pos/flag/lAcc=0
//    -> grid.sync
// C: bf16 MFMA GEMM-row + fused exp-sum; slice = HW XCC_ID (L2-local Y)
//    -> grid.sync
// D: finish (log + pos subtraction, original row order)
// ============================================================================
__global__ __launch_bounds__(1024, 4) void fused_kernel(
    const float4* __restrict__ fv4, const float4* __restrict__ fi4,
    const float4* __restrict__ v4,  const float4* __restrict__ vi4,
    uint2* __restrict__ Xb2, uint2* __restrict__ Yf0, uint2* __restrict__ Yf1,
    float* __restrict__ posArr, int* __restrict__ origArr, int* __restrict__ flagArr,
    float* __restrict__ lAcc, float* __restrict__ out,
    int* __restrict__ cntArr, int* __restrict__ xcdCnt)
{
    __shared__ union {
        struct { unsigned T0[32 * 66]; unsigned T1[32 * 66]; } a;  // phase A transpose
        struct { uint4 Xf[4][1024]; } c;                           // phase C frag tiles
        char pad[86016];                                           // 84 KB => 1 block/CU
    } U;
    __shared__ int sFlagL[32];
    __shared__ int sRank[32];
    __shared__ int sPre;
    __shared__ int sRkx;
    __shared__ int sFlagC[4][64];
    __shared__ int sHasC[4][2];

    const int t    = threadIdx.x;
    const int pb   = blockIdx.x;
    const int wave = t >> 6;
    const int lane = t & 63;
    const int half = lane >> 5;
    const int c    = lane & 31;
    const int rl   = wave * 2 + half;          // row-local 0..31
    const int b    = pb * 32 + rl;             // global row
    const int src  = b * 32 + c;               // float4 index into [B,128]

    // ---------------- phase A: normalize + select + Yf transpose ----------------
    if (pb == 0 && t < 8) xcdCnt[t] = 0;       // visible after sync1, used after sync2

    const float4 afv = fv4[src];
    const float4 afi = fi4[src];
    const float4 av  = v4[src];
    const float4 avi = vi4[src];

    float nfv = afv.x*afv.x + afv.y*afv.y + afv.z*afv.z + afv.w*afv.w;
    float nfi = afi.x*afi.x + afi.y*afi.y + afi.z*afi.z + afi.w*afi.w;
    float nv  = av.x*av.x   + av.y*av.y   + av.z*av.z   + av.w*av.w;
    float nvi = avi.x*avi.x + avi.y*avi.y + avi.z*avi.z + avi.w*avi.w;
    float dv  = afv.x*av.x  + afv.y*av.y  + afv.z*av.z  + afv.w*av.w;
    float di  = afi.x*avi.x + afi.y*avi.y + afi.z*avi.z + afi.w*avi.w;

    #pragma unroll
    for (int m = 1; m < 32; m <<= 1) {   // half-wave butterfly (row = 32-lane group)
        nfv += __shfl_xor(nfv, m);
        nfi += __shfl_xor(nfi, m);
        nv  += __shfl_xor(nv,  m);
        nvi += __shfl_xor(nvi, m);
        dv  += __shfl_xor(dv,  m);
        di  += __shfl_xor(di,  m);
    }

    const float rnfv = 1.0f / fmaxf(sqrtf(nfv), 1e-12f);
    const float rnfi = 1.0f / fmaxf(sqrtf(nfi), 1e-12f);
    const float rnv  = 1.0f / fmaxf(sqrtf(nv ), 1e-12f);
    const float rnvi = 1.0f / fmaxf(sqrtf(nvi), 1e-12f);

    const float pos_v = dv * rnfv * rnv;
    const float pos_i = di * rnfi * rnvi;
    const bool useV = (pos_v >= pos_i);
    const float pos = useV ? pos_v : pos_i;
    const float sc  = useV ? rnfv : rnfi;      // held across sync (tiny live set)

    *(uint2*)&U.a.T0[rl * 66 + c * 2] =
        make_uint2(pack_bf16(av.x * rnv,  av.y * rnv),  pack_bf16(av.z * rnv,  av.w * rnv));
    *(uint2*)&U.a.T1[rl * 66 + c * 2] =
        make_uint2(pack_bf16(avi.x * rnvi, avi.y * rnvi), pack_bf16(avi.z * rnvi, avi.w * rnvi));
    if (c == 0) sFlagL[rl] = useV ? 0 : 1;
    __syncthreads();

    if (t < 64) {                               // wave 0: local ranks + count store
        const int f = (lane < 32) ? sFlagL[lane] : 2;
        const unsigned long long m0 = __ballot(f == 0);
        const unsigned long long m1 = __ballot(f == 1);
        if (lane == 0) cntArr[pb] = (int)__popcll(m0);
        if (lane < 32) {
            const unsigned long long below = (1ull << lane) - 1ull;
            sRank[lane] = (f == 0) ? (int)__popcll(m0 & below) : (int)__popcll(m1 & below);
        }
    }
    // fragment-ordered Yf write (coalesced; reads T0/T1 staged above)
    {
        const int tl = t >> 9;
        const int kc = (t >> 7) & 3;
        const int lp = (t >> 1) & 63;
        const int w0 = (t & 1) * 2;
        const int row = tl * 16 + (lp & 15);
        const int s   = kc * 16 + (lp >> 4) * 4 + w0;
        Yf0[pb * 1024 + t] = *(const uint2*)&U.a.T0[row * 66 + s];
        Yf1[pb * 1024 + t] = *(const uint2*)&U.a.T1[row * 66 + s];
    }

    cg::this_grid().sync();   // ---- sync1 ----

    // ---------------- phase B: deterministic compaction + Xb write ----------------
    if (t < 64) {
        int s = 0;
        #pragma unroll
        for (int j = 0; j < 4; ++j) {
            const int idx2 = lane + j * 64;
            if (idx2 < pb) s += cntArr[idx2];
        }
        #pragma unroll
        for (int m = 1; m < 64; m <<= 1) s += __shfl_xor(s, m);
        if (lane == 0) sPre = s;
    }
    __syncthreads();

    const int f0 = useV ? 0 : 1;
    const int rk = sRank[rl];
    const int pre0 = sPre;
    const int p = (f0 == 0) ? (pre0 + rk)
                            : (Bsz - 1 - (32 * pb - pre0 + rk));

    const float4 ax = useV ? fv4[src] : fi4[src];   // L2/L3-warm reload
    Xb2[p * 32 + c] = make_uint2(pack_bf16(ax.x * sc, ax.y * sc),
                                 pack_bf16(ax.z * sc, ax.w * sc));
    if (c == 0) {
        posArr[p]  = pos;
        origArr[p] = b;
        flagArr[p] = f0;
        lAcc[p]    = 0.0f;
    }

    cg::this_grid().sync();   // ---- sync2 ----

    // ---------------- phase C: MFMA GEMM-row + exp-sum ----------------
    unsigned xcc;
    asm volatile("s_getreg_b32 %0, hwreg(HW_REG_XCC_ID)" : "=s"(xcc));
    xcc &= 7;
    if (t == 0) sRkx = atomicAdd(&xcdCnt[xcc], 1);   // 0..31 within this XCD
    if (t < 8) sHasC[t >> 1][t & 1] = 0;
    __syncthreads();

    const int vb = t >> 8;           // virtual main-block 0..3 (4 waves each)
    const int tl = t & 255;
    const int wl = (t >> 6) & 3;     // wave within virtual block
    const int quad = lane >> 4;
    const int mrow = lane & 15;
    const int rowblk = sRkx * 4 + vb;          // 0..127
    const int p0 = rowblk * 64;
    const int slice = (int)xcc;                // guaranteed-local Y slice

    if (tl < 64) {
        const int ff = flagArr[p0 + tl];
        sFlagC[vb][tl] = ff;
        atomicOr(&sHasC[vb][ff], 1);
    }
    // stage X tile into fragment order with rot2 swizzle
    #pragma unroll
    for (int it = 0; it < 4; ++it) {
        const int i = tl + it * 256;
        const int row = i >> 4, ch = i & 15;
        const uint4 val = ((const uint4*)Xb2)[(p0 + row) * 16 + ch];
        const int blk16 = (row >> 4) * 4 + (ch >> 2);
        const int slot  = (ch & 3) * 16 + (row & 15);
        U.c.Xf[vb][blk16 * 64 + ROT2(slot)] = val;
    }
    __syncthreads();

    short8 afr[4][4];
    #pragma unroll
    for (int rt = 0; rt < 4; ++rt)
        #pragma unroll
        for (int kc = 0; kc < 4; ++kc)
            afr[rt][kc] = *(const short8*)&U.c.Xf[vb][(rt * 4 + kc) * 64 + ROT2(lane)];

    unsigned frmask = 0;
    #pragma unroll
    for (int rt = 0; rt < 4; ++rt)
        #pragma unroll
        for (int r = 0; r < 4; ++r)
            frmask |= (unsigned)sFlagC[vb][rt * 16 + quad * 4 + r] << (rt * 4 + r);

    float rowsum[4][4] = {};
    const int g0 = slice * 64 + wl * 16;

    for (int phase = 0; phase < 2; ++phase) {
        if (!sHasC[vb][phase]) continue;       // wave-uniform skip
        const uint4* __restrict__ yb =
            (const uint4*)(phase ? Yf1 : Yf0) + (size_t)g0 * 256 + lane;

        short8 b0 = *(const short8*)&yb[0];
        short8 b1 = *(const short8*)&yb[64];
        short8 b2 = *(const short8*)&yb[128];
        short8 b3 = *(const short8*)&yb[192];

        #pragma unroll 1
        for (int jt = 0; jt < 16; ++jt) {
            float4v acc[4] = {};
            #pragma unroll
            for (int rt = 0; rt < 4; ++rt)
                acc[rt] = __builtin_amdgcn_mfma_f32_16x16x32_bf16(afr[rt][0], b0, acc[rt], 0, 0, 0);
            #pragma unroll
            for (int rt = 0; rt < 4; ++rt)
                acc[rt] = __builtin_amdgcn_mfma_f32_16x16x32_bf16(afr[rt][1], b1, acc[rt], 0, 0, 0);
            if (jt < 15) { b0 = *(const short8*)&yb[256]; b1 = *(const short8*)&yb[320]; }
            #pragma unroll
            for (int rt = 0; rt < 4; ++rt)
                acc[rt] = __builtin_amdgcn_mfma_f32_16x16x32_bf16(afr[rt][2], b2, acc[rt], 0, 0, 0);
            #pragma unroll
            for (int rt = 0; rt < 4; ++rt)
                acc[rt] = __builtin_amdgcn_mfma_f32_16x16x32_bf16(afr[rt][3], b3, acc[rt], 0, 0, 0);
            if (jt < 15) { b2 = *(const short8*)&yb[384]; b3 = *(const short8*)&yb[448]; }
            yb += 256;

            // branchless gated exp-sum, fixed shift C = 1/T
            #pragma unroll
            for (int rt = 0; rt < 4; ++rt)
                #pragma unroll
                for (int r = 0; r < 4; ++r) {
                    const float e = __expf(acc[rt][r] * INV_T - INV_T);
                    rowsum[rt][r] += ((int)((frmask >> (rt * 4 + r)) & 1u) == phase) ? e : 0.0f;
                }
        }
    }

    #pragma unroll
    for (int m = 1; m < 16; m <<= 1)
        #pragma unroll
        for (int rt = 0; rt < 4; ++rt)
            #pragma unroll
            for (int r = 0; r < 4; ++r)
                rowsum[rt][r] += __shfl_xor(rowsum[rt][r], m);

    if (mrow == 0) {
        #pragma unroll
        for (int rt = 0; rt < 4; ++rt)
            #pragma unroll
            for (int r = 0; r < 4; ++r)
                atomicAdd(&lAcc[p0 + rt * 16 + quad * 4 + r], rowsum[rt][r]);
    }

    cg::this_grid().sync();   // ---- sync3 ----

    // ---------------- phase D: finish ----------------
    if (t < 32) {
        const int p2 = pb * 32 + t;
        out[origArr[p2]] = logf(lAcc[p2]) + INV_T - posArr[p2] * INV_T;
    }
}

// ---------------- launch ----------------
extern "C" void kernel_launch(void* const* d_in, const int* in_sizes, int n_in,
                              void* d_out, int out_size, void* d_ws, size_t ws_size,
                              hipStream_t stream)
{
    const float4* fv = (const float4*)d_in[0];
    const float4* fi = (const float4*)d_in[1];
    const float4* v  = (const float4*)d_in[2];
    const float4* vi = (const float4*)d_in[3];
    float* out = (float*)d_out;

    unsigned short* XbU  = (unsigned short*)d_ws;    // [B,128] bf16 compacted X
    unsigned short* Yf0U = XbU  + Bsz * 128;         // [B*128] bf16 B-frag-ordered v
    unsigned short* Yf1U = Yf0U + Bsz * 128;         // [B*128] bf16 B-frag-ordered vi
    float* posArr = (float*)(Yf1U + Bsz * 128);      // [B]
    float* lAcc   = posArr + Bsz;                    // [B]
    int*  origArr = (int*)(lAcc + Bsz);              // [B]
    int*  flagArr = origArr + Bsz;                   // [B]
    int*  cntArr  = flagArr + Bsz;                   // [256] per-block flavor0 counts
    int*  xcdCnt  = cntArr + 256;                    // [8] rank-in-XCD counters

    uint2* Xb2 = (uint2*)XbU;
    uint2* Yf0 = (uint2*)Yf0U;
    uint2* Yf1 = (uint2*)Yf1U;

    void* kargs[] = {
        (void*)&fv, (void*)&fi, (void*)&v, (void*)&vi,
        (void*)&Xb2, (void*)&Yf0, (void*)&Yf1,
        (void*)&posArr, (void*)&origArr, (void*)&flagArr,
        (void*)&lAcc, (void*)&out, (void*)&cntArr, (void*)&xcdCnt
    };
    hipLaunchCooperativeKernel((void*)fused_kernel, dim3(256), dim3(1024),
                               kargs, 0, stream);
}